// Round 21
// baseline (201.237 us; speedup 1.0000x reference)
//
#include <hip/hip_runtime.h>
#include <hip/hip_bf16.h>

#define B_ 2
#define T_ 2048
#define C_ 2048
#define H_ 32
#define HK_ 4
#define D_ 64

typedef __attribute__((ext_vector_type(4)))  float f32x4;
typedef __attribute__((ext_vector_type(2)))  float f32x2;
typedef __attribute__((ext_vector_type(16))) float f32x16;
typedef __attribute__((ext_vector_type(8)))  short bf16x8;

static __device__ __forceinline__ unsigned short f2bf(float f) {
  union { __hip_bfloat16 h; unsigned short s; } u;
  u.h = __float2bfloat16(f);
  return u.s;
}
static __device__ __forceinline__ float bf2f(unsigned short s) {
  union { unsigned int u; float f; } u; u.u = ((unsigned int)s) << 16; return u.f;
}
static __device__ __forceinline__ unsigned int cvtpk(float lo, float hi) {
  unsigned int r;
  asm("v_cvt_pk_bf16_f32 %0, %1, %2" : "=v"(r) : "v"(lo), "v"(hi));
  return r;
}

#define GLD16(gp, lp) __builtin_amdgcn_global_load_lds( \
    (const __attribute__((address_space(1))) unsigned int*)(gp), \
    (__attribute__((address_space(3))) unsigned int*)(unsigned int)(uintptr_t)(lp), 16, 0, 0)

// ---------------------------------------------------------------------------
// Merged f32 -> bf16 convert (r14-verified)
// ---------------------------------------------------------------------------
__global__ void conv_all(const float* __restrict__ x,  const float* __restrict__ wq,
                         const float* __restrict__ wk, const float* __restrict__ wv,
                         const float* __restrict__ wo,
                         unsigned short* __restrict__ x_bf,
                         unsigned short* __restrict__ wqkv,
                         unsigned short* __restrict__ wo_bf) {
  const int i = blockIdx.x * blockDim.x + threadIdx.x;   // 4,456,448 total
  const float* src;
  unsigned short* dst;
  int off;
  if (i < 2097152)      { src = x;  dst = x_bf;                  off = i; }
  else if (i < 3145728) { src = wq; dst = wqkv;                  off = i - 2097152; }
  else if (i < 3276800) { src = wk; dst = wqkv + 2048 * 2048;    off = i - 3145728; }
  else if (i < 3407872) { src = wv; dst = wqkv + 2304 * 2048;    off = i - 3276800; }
  else                  { src = wo; dst = wo_bf;                 off = i - 3407872; }
  f32x4 v = *(const f32x4*)(src + 4 * (size_t)off);
  ushort4 o;
  o.x = f2bf(v[0]); o.y = f2bf(v[1]); o.z = f2bf(v[2]); o.w = f2bf(v[3]);
  *(ushort4*)(dst + 4 * (size_t)off) = o;
}

// ---------------------------------------------------------------------------
// QKV GEMM: r19-rate plain epilogue for the q segment (contiguous bf16 into
// row-major qkv_bf, NO transpose, NO rope — rope moves to attention's Q load);
// k segment keeps fused RoPE (f32-accurate kout + k_bf), v keeps slot-reorder.
// Core loop = r6/r19 config (67us-measured): 128x128, BK=32, 4 waves, 3-buf
// 48KB LDS, counted vmcnt(4), one barrier/tile, chunk-XOR swizzle, setprio.
// ---------------------------------------------------------------------------
__global__ __launch_bounds__(256, 3)
void gemm_qkv(const unsigned short* __restrict__ A, const unsigned short* __restrict__ W,
              int M, int N, int K,
              const float* __restrict__ cosT, const float* __restrict__ sinT,
              unsigned short* __restrict__ qkvb, unsigned short* __restrict__ kbf,
              unsigned short* __restrict__ vtb, float* __restrict__ koutf,
              float* __restrict__ voutf) {
  __shared__ unsigned short As[3][128 * 32];
  __shared__ unsigned short Ws[3][128 * 32];

  const int tid  = threadIdx.x;
  const int lane = tid & 63;
  const int w    = tid >> 6;
  const int wm   = w >> 1, wn = w & 1;
  const int g    = lane >> 4;
  const int lr   = lane & 15;

  const int bm = blockIdx.y * 128;
  const int bn = blockIdx.x * 128;

  const int srow = tid >> 2;                  // 0..63
  const int sc   = (tid & 3) ^ (srow & 3);    // pre-swizzled 16B chunk
  const unsigned short* Ag = A + (size_t)(bm + srow) * K + sc * 8;
  const unsigned short* Wg = W + (size_t)(bn + srow) * K + sc * 8;

#define STAGEQ(buf, k0) do { \
    GLD16(Ag + (k0),                  &As[buf][       w * 512]); \
    GLD16(Ag + (size_t)64 * K + (k0), &As[buf][2048 + w * 512]); \
    GLD16(Wg + (k0),                  &Ws[buf][       w * 512]); \
    GLD16(Wg + (size_t)64 * K + (k0), &Ws[buf][2048 + w * 512]); \
  } while (0)

  f32x4 acc[4][4] = {};

  const int nt = K >> 5;          // 64
  STAGEQ(0, 0);
  STAGEQ(1, 32);

  for (int t = 0; t < nt; ++t) {
    if (t + 1 < nt) asm volatile("s_waitcnt vmcnt(4)" ::: "memory");
    else            asm volatile("s_waitcnt vmcnt(0)" ::: "memory");
    asm volatile("s_barrier" ::: "memory");

    if (t + 2 < nt) {
      const int nb = (t + 2) % 3;
      STAGEQ(nb, (size_t)(t + 2) * 32);
    }

    const unsigned short* At = &As[t % 3][0];
    const unsigned short* Wt = &Ws[t % 3][0];

    bf16x8 af[4], wf[4];
#pragma unroll
    for (int m = 0; m < 4; m++) {
      const int row = wm * 64 + m * 16 + lr;
      af[m] = *(const bf16x8*)&At[row * 32 + ((g ^ (row & 3)) << 3)];
    }
#pragma unroll
    for (int n = 0; n < 4; n++) {
      const int row = wn * 64 + n * 16 + lr;
      wf[n] = *(const bf16x8*)&Wt[row * 32 + ((g ^ (row & 3)) << 3)];
    }
    __builtin_amdgcn_s_setprio(1);
#pragma unroll
    for (int m = 0; m < 4; m++)
#pragma unroll
      for (int n = 0; n < 4; n++)
        acc[m][n] = __builtin_amdgcn_mfma_f32_16x16x32_bf16(af[m], wf[n], acc[m][n], 0, 0, 0);
    __builtin_amdgcn_s_setprio(0);
  }
#undef STAGEQ

  // ---- epilogue. C/D layout: col = lane&15, row = 4*(lane>>4)+reg ----
  const int seg = (bn < 2048) ? 0 : (bn < 2304 ? 1 : 2);
  if (seg == 0) {
    // q segment: PLAIN contiguous bf16 store into row-major qkv_bf (un-roped)
#pragma unroll
    for (int m = 0; m < 4; m++) {
      const int row = bm + wm * 64 + m * 16 + g * 4;
#pragma unroll
      for (int n = 0; n < 4; n++) {
        const int col = bn + wn * 64 + n * 16 + lr;
#pragma unroll
        for (int r = 0; r < 4; r++)
          qkvb[(size_t)(row + r) * 2560 + col] = f2bf(acc[m][n][r]);
      }
    }
  } else {
#pragma unroll
    for (int m = 0; m < 4; m++) {
#pragma unroll
      for (int n = 0; n < 4; n++) {
        const int col = bn + wn * 64 + n * 16 + lr;
        const int d   = col & 63;
#pragma unroll
        for (int r = 0; r < 4; r++) {
          const int row = bm + wm * 64 + m * 16 + g * 4 + r;
          const int tt  = row & (T_ - 1);
          const int bb  = row >> 11;
          const float val = acc[m][n][r];
          if (seg == 2) {
            const int hk = (col >> 6) - 36;
            const size_t idx = ((size_t)(bb * HK_ + hk) * T_ + tt) * D_ + d;
            voutf[idx] = val;
            const int tm   = tt & 15;
            const int tpos = (tt & ~15) | ((tm & 3) + ((tm >> 3) << 2) + ((tm & 4) << 1));
            vtb[((size_t)(bb * HK_ + hk) * D_ + d) * T_ + tpos] = f2bf(val);
          } else {
            const float cs = cosT[tt * D_ + d];
            const float sn = sinT[tt * D_ + d];
            const float other = __shfl_xor(val, 1);
            const float o = val * cs + ((lr & 1) ? other : -other) * sn;
            const int hk = (col >> 6) - 32;
            const size_t idx = ((size_t)(bb * HK_ + hk) * T_ + tt) * D_ + d;
            koutf[idx] = o;
            kbf[idx]   = f2bf(o);
          }
        }
      }
    }
  }
}

// ---------------------------------------------------------------------------
// WO GEMM — standalone, r6/r19 core, plain f32 epilogue.
// ---------------------------------------------------------------------------
__global__ __launch_bounds__(256, 3)
void gemm_wo(const unsigned short* __restrict__ A, const unsigned short* __restrict__ W,
             float* __restrict__ Cf, int M, int N, int K) {
  __shared__ unsigned short As[3][128 * 32];
  __shared__ unsigned short Ws[3][128 * 32];

  const int tid  = threadIdx.x;
  const int lane = tid & 63;
  const int w    = tid >> 6;
  const int wm   = w >> 1, wn = w & 1;
  const int g    = lane >> 4;
  const int lr   = lane & 15;

  const int bm = blockIdx.y * 128;
  const int bn = blockIdx.x * 128;

  const int srow = tid >> 2;
  const int sc   = (tid & 3) ^ (srow & 3);
  const unsigned short* Ag = A + (size_t)(bm + srow) * K + sc * 8;
  const unsigned short* Wg = W + (size_t)(bn + srow) * K + sc * 8;

#define STAGEW(buf, k0) do { \
    GLD16(Ag + (k0),                  &As[buf][       w * 512]); \
    GLD16(Ag + (size_t)64 * K + (k0), &As[buf][2048 + w * 512]); \
    GLD16(Wg + (k0),                  &Ws[buf][       w * 512]); \
    GLD16(Wg + (size_t)64 * K + (k0), &Ws[buf][2048 + w * 512]); \
  } while (0)

  f32x4 acc[4][4] = {};

  const int nt = K >> 5;
  STAGEW(0, 0);
  STAGEW(1, 32);

  for (int t = 0; t < nt; ++t) {
    if (t + 1 < nt) asm volatile("s_waitcnt vmcnt(4)" ::: "memory");
    else            asm volatile("s_waitcnt vmcnt(0)" ::: "memory");
    asm volatile("s_barrier" ::: "memory");

    if (t + 2 < nt) {
      const int nb = (t + 2) % 3;
      STAGEW(nb, (size_t)(t + 2) * 32);
    }

    const unsigned short* At = &As[t % 3][0];
    const unsigned short* Wt = &Ws[t % 3][0];

    bf16x8 af[4], wf[4];
#pragma unroll
    for (int m = 0; m < 4; m++) {
      const int row = wm * 64 + m * 16 + lr;
      af[m] = *(const bf16x8*)&At[row * 32 + ((g ^ (row & 3)) << 3)];
    }
#pragma unroll
    for (int n = 0; n < 4; n++) {
      const int row = wn * 64 + n * 16 + lr;
      wf[n] = *(const bf16x8*)&Wt[row * 32 + ((g ^ (row & 3)) << 3)];
    }
    __builtin_amdgcn_s_setprio(1);
#pragma unroll
    for (int m = 0; m < 4; m++)
#pragma unroll
      for (int n = 0; n < 4; n++)
        acc[m][n] = __builtin_amdgcn_mfma_f32_16x16x32_bf16(af[m], wf[n], acc[m][n], 0, 0, 0);
    __builtin_amdgcn_s_setprio(0);
  }
#undef STAGEW

#pragma unroll
  for (int m = 0; m < 4; m++) {
    const int row = bm + wm * 64 + m * 16 + g * 4;
#pragma unroll
    for (int n = 0; n < 4; n++) {
      const int col = bn + wn * 64 + n * 16 + lr;
#pragma unroll
      for (int r = 0; r < 4; r++)
        Cf[(size_t)(row + r) * N + col] = acc[m][n][r];
    }
  }
}

// ---------------------------------------------------------------------------
// One q-block step against a staged KV tile (r15-verified)
// ---------------------------------------------------------------------------
static __device__ __forceinline__ void attn_qstep(
    const unsigned short* __restrict__ Kt, const unsigned short* __restrict__ Vt,
    const bf16x8 (&qf)[4], f32x16& o0, f32x16& o1,
    float& m, float& l, float& c1,
    const int qrow, const int kb0, const bool last,
    const int qi, const int hi, const int swz) {
  const float SC   = 0.125f * 1.44269504089f;
  const float THRR = 44.3614195f;
  const int  qtop  = (qrow & ~31) + 31;
  const bool has1  = (kb0 + 32 <= qtop);

  f32x16 st0 = {}, st1 = {};
  __builtin_amdgcn_s_setprio(1);
#pragma unroll
  for (int c = 0; c < 4; c++) {
    bf16x8 kf = *(const bf16x8*)&Kt[qi * 64 + (((hi + 2 * c) ^ swz) << 3)];
    st0 = __builtin_amdgcn_mfma_f32_32x32x16_bf16(kf, qf[c], st0, 0, 0, 0);
  }
  if (!last || has1) {
#pragma unroll
    for (int c = 0; c < 4; c++) {
      bf16x8 kf = *(const bf16x8*)&Kt[(32 + qi) * 64 + (((hi + 2 * c) ^ swz) << 3)];
      st1 = __builtin_amdgcn_mfma_f32_32x32x16_bf16(kf, qf[c], st1, 0, 0, 0);
    }
  }
  __builtin_amdgcn_s_setprio(0);

  if (last) {
#pragma unroll
    for (int r = 0; r < 16; ++r) {
      const int key = kb0 + (r & 3) + 8 * (r >> 2) + 4 * hi;
      st0[r] = (key      <= qrow) ? st0[r] : -1e30f;
      st1[r] = (key + 32 <= qrow) ? st1[r] : -1e30f;
    }
  }

  float tmax = fmaxf(st0[0], st0[1]);
#pragma unroll
  for (int r = 2; r < 16; ++r) tmax = fmaxf(tmax, st0[r]);
#pragma unroll
  for (int r = 0; r < 16; ++r) tmax = fmaxf(tmax, st1[r]);
  tmax = fmaxf(tmax, __shfl_xor(tmax, 32));

  if (!__all(tmax <= m + THRR)) {
    const float mnew = fmaxf(m, tmax);
    const float al   = __builtin_amdgcn_exp2f((m - mnew) * SC);
#pragma unroll
    for (int r = 0; r < 16; ++r) { o0[r] *= al; o1[r] *= al; }
    l *= al;
    m  = mnew;
    c1 = -m * SC;
  }

  float sum = 0.f;
#pragma unroll
  for (int r = 0; r < 16; ++r) { float pv = __builtin_amdgcn_exp2f(__builtin_fmaf(st0[r], SC, c1)); st0[r] = pv; sum += pv; }
#pragma unroll
  for (int r = 0; r < 16; ++r) { float pv = __builtin_amdgcn_exp2f(__builtin_fmaf(st1[r], SC, c1)); st1[r] = pv; sum += pv; }
  sum += __shfl_xor(sum, 32);
  l += sum;

  union U8 { bf16x8 v; unsigned int u[4]; };
  U8 pf[4];
#pragma unroll
  for (int j = 0; j < 4; ++j) {
    pf[0].u[j] = cvtpk(st0[2 * j],     st0[2 * j + 1]);
    pf[1].u[j] = cvtpk(st0[8 + 2 * j], st0[8 + 2 * j + 1]);
    pf[2].u[j] = cvtpk(st1[2 * j],     st1[2 * j + 1]);
    pf[3].u[j] = cvtpk(st1[8 + 2 * j], st1[8 + 2 * j + 1]);
  }

  const int ncf = (!last || has1) ? 4 : 2;
  __builtin_amdgcn_s_setprio(1);
#pragma unroll
  for (int dh = 0; dh < 2; ++dh) {
    const unsigned short* Vrow = &Vt[(dh * 32 + qi) * 64];
    f32x16 oc = dh ? o1 : o0;
#pragma unroll
    for (int c = 0; c < 4; ++c) {
      if (c >= ncf) break;
      bf16x8 vf = *(const bf16x8*)&Vrow[(((2 * c + hi) ^ swz) << 3)];
      oc = __builtin_amdgcn_mfma_f32_32x32x16_bf16(vf, pf[c].v, oc, 0, 0, 0);
    }
    if (dh) o1 = oc; else o0 = oc;
  }
  __builtin_amdgcn_s_setprio(0);
}

// ---------------------------------------------------------------------------
// Flash attention v6: r15 pairing structure + in-register Q RoPE at load
// (Q read from row-major qkv_bf; pairs (2j,2j+1) are in-lane, no shuffles).
// ---------------------------------------------------------------------------
__global__ __launch_bounds__(512, 2)
void gqa_attn6(const unsigned short* __restrict__ qkv,
               const float* __restrict__ cosT, const float* __restrict__ sinT,
               const unsigned short* __restrict__ kb,
               const unsigned short* __restrict__ vt,
               unsigned short* __restrict__ ob) {
  __shared__ unsigned short Ks[3][4096];
  __shared__ unsigned short Vs[3][4096];

  const int tid  = threadIdx.x;
  const int lane = tid & 63;
  const int w    = tid >> 6;
  const int qi   = lane & 31;
  const int hi   = lane >> 5;

  const int go = blockIdx.x & 7;
  const int pp = blockIdx.x >> 3;
  const int b  = go >> 2;
  const int hk = go & 3;
  const int h  = hk * 8 + w;
  const int bh = b * H_ + h;

  const int qbaseA = (63 - pp) * 32;
  const int qbaseB = pp * 32;
  const int qrowA  = qbaseA + qi;
  const int qrowB  = qbaseB + qi;

  // Q load from row-major qkv (stride 2560) + in-register RoPE
  bf16x8 qfA[4], qfB[4];
  {
    const unsigned short* qpA = qkv + ((size_t)(b * T_ + qrowA)) * 2560 + h * D_ + 8 * hi;
    const unsigned short* qpB = qkv + ((size_t)(b * T_ + qrowB)) * 2560 + h * D_ + 8 * hi;
    const float* cA = cosT + qrowA * D_ + 8 * hi;
    const float* sA = sinT + qrowA * D_ + 8 * hi;
    const float* cB = cosT + qrowB * D_ + 8 * hi;
    const float* sB = sinT + qrowB * D_ + 8 * hi;
#pragma unroll
    for (int c = 0; c < 4; c++) {
      const bf16x8 ra = *(const bf16x8*)(qpA + 16 * c);
      const bf16x8 rb = *(const bf16x8*)(qpB + 16 * c);
#pragma unroll
      for (int j = 0; j < 4; j++) {
        const int dd = 16 * c + 2 * j;
        {
          const float x1 = bf2f((unsigned short)ra[2 * j]);
          const float x2 = bf2f((unsigned short)ra[2 * j + 1]);
          const float cc = cA[dd], ss = sA[dd];
          qfA[c][2 * j]     = (short)f2bf(x1 * cc - x2 * ss);
          qfA[c][2 * j + 1] = (short)f2bf(x2 * cc + x1 * ss);
        }
        {
          const float x1 = bf2f((unsigned short)rb[2 * j]);
          const float x2 = bf2f((unsigned short)rb[2 * j + 1]);
          const float cc = cB[dd], ss = sB[dd];
          qfB[c][2 * j]     = (short)f2bf(x1 * cc - x2 * ss);
          qfB[c][2 * j + 1] = (short)f2bf(x2 * cc + x1 * ss);
        }
      }
    }
  }

  const int srow   = lane >> 3;
  const int schunk = (lane & 7) ^ srow;
  const int krow   = 8 * w + srow;
  const unsigned short* gK = kb + (size_t)(b * HK_ + hk) * T_ * D_ + (size_t)krow * D_ + schunk * 8;
  const unsigned short* gV = vt + (size_t)(b * HK_ + hk) * D_ * T_ + (size_t)krow * T_ + schunk * 8;
  unsigned short* ldsK = &Ks[0][w * 512];
  unsigned short* ldsV = &Vs[0][w * 512];

#define STAGE_KV(pbuf, kk0) do { \
    GLD16(gK + (size_t)(kk0) * D_, ldsK + (pbuf) * 4096); \
    GLD16(gV + (kk0),              ldsV + (pbuf) * 4096); \
  } while (0)

  f32x16 o0A = {}, o1A = {}, o0B = {}, o1B = {};
  float mA = -1e30f, lA = 0.f, c1A = 0.f;
  float mB = -1e30f, lB = 0.f, c1B = 0.f;
  const int swz = qi & 7;

  const int ntA = ((qbaseA + 31) >> 6) + 1;
  const int ntB = ((qbaseB + 31) >> 6) + 1;

  STAGE_KV(0, 0);
  if (ntA > 1) STAGE_KV(1, 64);

  int p = 0;
  for (int it = 0; it < ntA; ++it) {
    const int kb0 = it * 64;

    asm volatile("s_waitcnt lgkmcnt(0)" ::: "memory");
    if (it + 1 < ntA) asm volatile("s_waitcnt vmcnt(2)" ::: "memory");
    else              asm volatile("s_waitcnt vmcnt(0)" ::: "memory");
    asm volatile("s_barrier" ::: "memory");
    if (it + 2 < ntA) STAGE_KV((p + 2 > 2) ? p - 1 : p + 2, kb0 + 128);

    const unsigned short* Kt = &Ks[0][0] + p * 4096;
    const unsigned short* Vt = &Vs[0][0] + p * 4096;

    attn_qstep(Kt, Vt, qfA, o0A, o1A, mA, lA, c1A, qrowA, kb0, it == ntA - 1, qi, hi, swz);
    if (it < ntB)
      attn_qstep(Kt, Vt, qfB, o0B, o1B, mB, lB, c1B, qrowB, kb0, it == ntB - 1, qi, hi, swz);

    p = (p > 1) ? 0 : p + 1;
  }

  const float invA = 1.0f / lA;
  const float invB = 1.0f / lB;
  unsigned short* orowA = ob + (size_t)(b * T_ + qrowA) * (H_ * D_) + h * D_;
  unsigned short* orowB = ob + (size_t)(b * T_ + qrowB) * (H_ * D_) + h * D_;
#pragma unroll
  for (int dh = 0; dh < 2; ++dh) {
    const f32x16 ovA = dh ? o1A : o0A;
    const f32x16 ovB = dh ? o1B : o0B;
#pragma unroll
    for (int rg = 0; rg < 4; ++rg) {
      const int d0 = 32 * dh + 8 * rg + 4 * hi;
      ushort4 pkA, pkB;
      pkA.x = f2bf(ovA[4 * rg + 0] * invA);
      pkA.y = f2bf(ovA[4 * rg + 1] * invA);
      pkA.z = f2bf(ovA[4 * rg + 2] * invA);
      pkA.w = f2bf(ovA[4 * rg + 3] * invA);
      pkB.x = f2bf(ovB[4 * rg + 0] * invB);
      pkB.y = f2bf(ovB[4 * rg + 1] * invB);
      pkB.z = f2bf(ovB[4 * rg + 2] * invB);
      pkB.w = f2bf(ovB[4 * rg + 3] * invB);
      *(ushort4*)(orowA + d0) = pkA;
      *(ushort4*)(orowB + d0) = pkB;
    }
  }
#undef STAGE_KV
}

// ---------------------------------------------------------------------------
extern "C" void kernel_launch(void* const* d_in, const int* in_sizes, int n_in,
                              void* d_out, int out_size, void* d_ws, size_t ws_size,
                              hipStream_t stream) {
  const float* x    = (const float*)d_in[0];
  const float* cosT = (const float*)d_in[1];
  const float* sinT = (const float*)d_in[2];
  const float* wq   = (const float*)d_in[3];
  const float* wk   = (const float*)d_in[4];
  const float* wv   = (const float*)d_in[5];
  const float* wo   = (const float*)d_in[6];

  float* y    = (float*)d_out;                                  // B*T*C
  float* kout = (float*)d_out + (size_t)B_ * T_ * C_;           // B*Hk*T*D f32
  float* vout = kout + (size_t)B_ * HK_ * T_ * D_;              // B*Hk*T*D f32

  // Workspace (peak 60,817,408 B; r0-validated layout reached 62.9 MB OK):
  //  [0,16M)        x_bf  -> (after QKV GEMM) o_bf
  //  [16M,26M)      wqkv
  //  [26M,46M)      qkv_bf (q segment live through attention)
  //  [46M,48M)      k_bf   [48M,50M) v_t   [50M,58M) wo_bf
  char* ws = (char*)d_ws;
  unsigned short* x_bf   = (unsigned short*)(ws);               // 16,777,216
  unsigned short* o_bf   = x_bf;                                // reuse after QKV
  unsigned short* wqkv   = (unsigned short*)(ws + 16777216);    // 10,485,760
  unsigned short* qkv_bf = (unsigned short*)(ws + 27262976);    // 20,971,520
  unsigned short* k_bf   = (unsigned short*)(ws + 48234496);    //  2,097,152
  unsigned short* v_t    = (unsigned short*)(ws + 50331648);    //  2,097,152
  unsigned short* wo_bf  = (unsigned short*)(ws + 52428800);    //  8,388,608 -> 60,817,408

  const int M = B_ * T_;  // 4096

  conv_all<<<17408, 256, 0, stream>>>(x, wq, wk, wv, wo, x_bf, wqkv, wo_bf);

  // QKV GEMM: q -> plain row-major bf16 (un-roped); k -> fused RoPE; v -> reorder
  gemm_qkv<<<dim3(2560 / 128, M / 128), 256, 0, stream>>>(
      x_bf, wqkv, M, 2560, C_, cosT, sinT, qkv_bf, k_bf, v_t, kout, vout);

  // paired-causal flash attention with in-register Q RoPE at load
  gqa_attn6<<<256, 512, 0, stream>>>(qkv_bf, cosT, sinT, k_bf, v_t, o_bf);

  // WO GEMM: M=4096, N=2048, K=2048
  gemm_wo<<<dim3(C_ / 128, M / 128), 256, 0, stream>>>(o_bf, wo_bf, y, M, C_, H_ * D_);
}

// Round 22
// 186.889 us; speedup vs baseline: 1.0768x; 1.0768x over previous
//
#include <hip/hip_runtime.h>
#include <hip/hip_bf16.h>

#define B_ 2
#define T_ 2048
#define C_ 2048
#define H_ 32
#define HK_ 4
#define D_ 64

typedef __attribute__((ext_vector_type(4)))  float f32x4;
typedef __attribute__((ext_vector_type(2)))  float f32x2;
typedef __attribute__((ext_vector_type(16))) float f32x16;
typedef __attribute__((ext_vector_type(8)))  short bf16x8;

static __device__ __forceinline__ unsigned short f2bf(float f) {
  union { __hip_bfloat16 h; unsigned short s; } u;
  u.h = __float2bfloat16(f);
  return u.s;
}
static __device__ __forceinline__ float bf2f(unsigned short s) {
  union { unsigned int u; float f; } u; u.u = ((unsigned int)s) << 16; return u.f;
}
static __device__ __forceinline__ unsigned int cvtpk(float lo, float hi) {
  unsigned int r;
  asm("v_cvt_pk_bf16_f32 %0, %1, %2" : "=v"(r) : "v"(lo), "v"(hi));
  return r;
}

#define GLD16(gp, lp) __builtin_amdgcn_global_load_lds( \
    (const __attribute__((address_space(1))) unsigned int*)(gp), \
    (__attribute__((address_space(3))) unsigned int*)(unsigned int)(uintptr_t)(lp), 16, 0, 0)

// ---------------------------------------------------------------------------
// Merged f32 -> bf16 convert (r14-verified)
// ---------------------------------------------------------------------------
__global__ void conv_all(const float* __restrict__ x,  const float* __restrict__ wq,
                         const float* __restrict__ wk, const float* __restrict__ wv,
                         const float* __restrict__ wo,
                         unsigned short* __restrict__ x_bf,
                         unsigned short* __restrict__ wqkv,
                         unsigned short* __restrict__ wo_bf) {
  const int i = blockIdx.x * blockDim.x + threadIdx.x;   // 4,456,448 total
  const float* src;
  unsigned short* dst;
  int off;
  if (i < 2097152)      { src = x;  dst = x_bf;                  off = i; }
  else if (i < 3145728) { src = wq; dst = wqkv;                  off = i - 2097152; }
  else if (i < 3276800) { src = wk; dst = wqkv + 2048 * 2048;    off = i - 3145728; }
  else if (i < 3407872) { src = wv; dst = wqkv + 2304 * 2048;    off = i - 3276800; }
  else                  { src = wo; dst = wo_bf;                 off = i - 3407872; }
  f32x4 v = *(const f32x4*)(src + 4 * (size_t)off);
  ushort4 o;
  o.x = f2bf(v[0]); o.y = f2bf(v[1]); o.z = f2bf(v[2]); o.w = f2bf(v[3]);
  *(ushort4*)(dst + 4 * (size_t)off) = o;
}

// ---------------------------------------------------------------------------
// GEMM (r11/r15 config — best measured): 128x128 tile, BK=32, 4 waves (2x2),
// TRIPLE-buffered 48KB LDS (3 blocks/CU), counted vmcnt(4), ONE s_barrier
// per tile, chunk-XOR swizzle, setprio, bijective XCD swizzle, 16x16x32.
// EPI: 0 = plain f32 C, 1 = fused QKV epilogue (RoPE q/k + v slot-reorder).
// ---------------------------------------------------------------------------
template<int EPI>
__global__ __launch_bounds__(256, 3)
void gemm3(const unsigned short* __restrict__ A, const unsigned short* __restrict__ W,
           int M, int N, int K,
           float* __restrict__ Cf,
           const float* __restrict__ cosT, const float* __restrict__ sinT,
           unsigned short* __restrict__ qb, unsigned short* __restrict__ kbf,
           unsigned short* __restrict__ vtb, float* __restrict__ koutf,
           float* __restrict__ voutf) {
  __shared__ unsigned short As[3][128 * 32];
  __shared__ unsigned short Ws[3][128 * 32];

  const int tid  = threadIdx.x;
  const int lane = tid & 63;
  const int w    = tid >> 6;
  const int wm   = w >> 1, wn = w & 1;
  const int g    = lane >> 4;
  const int lr   = lane & 15;

  // bijective XCD swizzle (grid sizes are multiples of 8)
  const int gx   = gridDim.x;
  const int flat = blockIdx.y * gx + blockIdx.x;
  const int cpx  = (gx * gridDim.y) >> 3;
  const int swzb = (flat & 7) * cpx + (flat >> 3);
  const int bm   = (swzb / gx) * 128;
  const int bn   = (swzb % gx) * 128;

  const int srow = tid >> 2;                  // 0..63
  const int sc   = (tid & 3) ^ (srow & 3);    // pre-swizzled 16B chunk
  const unsigned short* Ag = A + (size_t)(bm + srow) * K + sc * 8;
  const unsigned short* Wg = W + (size_t)(bn + srow) * K + sc * 8;

#define STAGE3(buf, k0) do { \
    GLD16(Ag + (k0),                  &As[buf][       w * 512]); \
    GLD16(Ag + (size_t)64 * K + (k0), &As[buf][2048 + w * 512]); \
    GLD16(Wg + (k0),                  &Ws[buf][       w * 512]); \
    GLD16(Wg + (size_t)64 * K + (k0), &Ws[buf][2048 + w * 512]); \
  } while (0)

  f32x4 acc[4][4] = {};

  const int nt = K >> 5;          // 64 for K=2048
  STAGE3(0, 0);
  STAGE3(1, 32);

  for (int t = 0; t < nt; ++t) {
    if (t + 1 < nt) asm volatile("s_waitcnt vmcnt(4)" ::: "memory");
    else            asm volatile("s_waitcnt vmcnt(0)" ::: "memory");
    asm volatile("s_barrier" ::: "memory");

    if (t + 2 < nt) {
      const int nb = (t + 2) % 3;
      STAGE3(nb, (size_t)(t + 2) * 32);
    }

    const unsigned short* At = &As[t % 3][0];
    const unsigned short* Wt = &Ws[t % 3][0];

    bf16x8 af[4], wf[4];
#pragma unroll
    for (int m = 0; m < 4; m++) {
      const int row = wm * 64 + m * 16 + lr;
      af[m] = *(const bf16x8*)&At[row * 32 + ((g ^ (row & 3)) << 3)];
    }
#pragma unroll
    for (int n = 0; n < 4; n++) {
      const int row = wn * 64 + n * 16 + lr;
      wf[n] = *(const bf16x8*)&Wt[row * 32 + ((g ^ (row & 3)) << 3)];
    }
    __builtin_amdgcn_s_setprio(1);
#pragma unroll
    for (int m = 0; m < 4; m++)
#pragma unroll
      for (int n = 0; n < 4; n++)
        acc[m][n] = __builtin_amdgcn_mfma_f32_16x16x32_bf16(af[m], wf[n], acc[m][n], 0, 0, 0);
    __builtin_amdgcn_s_setprio(0);
  }
#undef STAGE3

  // ---- epilogue. C/D layout: col = lane&15, row = 4*(lane>>4)+reg ----
  if (EPI == 0) {
#pragma unroll
    for (int m = 0; m < 4; m++) {
      const int row = bm + wm * 64 + m * 16 + g * 4;
#pragma unroll
      for (int n = 0; n < 4; n++) {
        const int col = bn + wn * 64 + n * 16 + lr;
#pragma unroll
        for (int r = 0; r < 4; r++)
          Cf[(size_t)(row + r) * N + col] = acc[m][n][r];
      }
    }
  } else {
    // segments (BN=128 never straddles): [0,2048)=q, [2048,2304)=k, [2304,2560)=v
    const int seg = (bn < 2048) ? 0 : (bn < 2304 ? 1 : 2);
#pragma unroll
    for (int m = 0; m < 4; m++) {
#pragma unroll
      for (int n = 0; n < 4; n++) {
        const int col = bn + wn * 64 + n * 16 + lr;
        const int d   = col & 63;
#pragma unroll
        for (int r = 0; r < 4; r++) {
          const int row = bm + wm * 64 + m * 16 + g * 4 + r;
          const int tt  = row & (T_ - 1);
          const int bb  = row >> 11;
          const float val = acc[m][n][r];
          if (seg == 2) {
            const int hk = (col >> 6) - 36;
            const size_t idx = ((size_t)(bb * HK_ + hk) * T_ + tt) * D_ + d;
            voutf[idx] = val;
            const int tm   = tt & 15;
            const int tpos = (tt & ~15) | ((tm & 3) + ((tm >> 3) << 2) + ((tm & 4) << 1));
            vtb[((size_t)(bb * HK_ + hk) * D_ + d) * T_ + tpos] = f2bf(val);
          } else {
            const float cs = cosT[tt * D_ + d];
            const float sn = sinT[tt * D_ + d];
            const float other = __shfl_xor(val, 1);
            const float o = val * cs + ((lr & 1) ? other : -other) * sn;
            if (seg == 0) {
              const int h = col >> 6;
              qb[((size_t)(bb * H_ + h) * T_ + tt) * D_ + d] = f2bf(o);
            } else {
              const int hk = (col >> 6) - 32;
              const size_t idx = ((size_t)(bb * HK_ + hk) * T_ + tt) * D_ + d;
              koutf[idx] = o;
              kbf[idx]   = f2bf(o);
            }
          }
        }
      }
    }
  }
}

// ---------------------------------------------------------------------------
// One q-block step against a staged KV tile (r15-verified)
// ---------------------------------------------------------------------------
static __device__ __forceinline__ void attn_qstep(
    const unsigned short* __restrict__ Kt, const unsigned short* __restrict__ Vt,
    const bf16x8 (&qf)[4], f32x16& o0, f32x16& o1,
    float& m, float& l, float& c1,
    const int qrow, const int kb0, const bool last,
    const int qi, const int hi, const int swz) {
  const float SC   = 0.125f * 1.44269504089f;
  const float THRR = 44.3614195f;
  const int  qtop  = (qrow & ~31) + 31;
  const bool has1  = (kb0 + 32 <= qtop);

  f32x16 st0 = {}, st1 = {};
  __builtin_amdgcn_s_setprio(1);
#pragma unroll
  for (int c = 0; c < 4; c++) {
    bf16x8 kf = *(const bf16x8*)&Kt[qi * 64 + (((hi + 2 * c) ^ swz) << 3)];
    st0 = __builtin_amdgcn_mfma_f32_32x32x16_bf16(kf, qf[c], st0, 0, 0, 0);
  }
  if (!last || has1) {
#pragma unroll
    for (int c = 0; c < 4; c++) {
      bf16x8 kf = *(const bf16x8*)&Kt[(32 + qi) * 64 + (((hi + 2 * c) ^ swz) << 3)];
      st1 = __builtin_amdgcn_mfma_f32_32x32x16_bf16(kf, qf[c], st1, 0, 0, 0);
    }
  }
  __builtin_amdgcn_s_setprio(0);

  if (last) {
#pragma unroll
    for (int r = 0; r < 16; ++r) {
      const int key = kb0 + (r & 3) + 8 * (r >> 2) + 4 * hi;
      st0[r] = (key      <= qrow) ? st0[r] : -1e30f;
      st1[r] = (key + 32 <= qrow) ? st1[r] : -1e30f;
    }
  }

  float tmax = fmaxf(st0[0], st0[1]);
#pragma unroll
  for (int r = 2; r < 16; ++r) tmax = fmaxf(tmax, st0[r]);
#pragma unroll
  for (int r = 0; r < 16; ++r) tmax = fmaxf(tmax, st1[r]);
  tmax = fmaxf(tmax, __shfl_xor(tmax, 32));

  if (!__all(tmax <= m + THRR)) {
    const float mnew = fmaxf(m, tmax);
    const float al   = __builtin_amdgcn_exp2f((m - mnew) * SC);
#pragma unroll
    for (int r = 0; r < 16; ++r) { o0[r] *= al; o1[r] *= al; }
    l *= al;
    m  = mnew;
    c1 = -m * SC;
  }

  float sum = 0.f;
#pragma unroll
  for (int r = 0; r < 16; ++r) { float pv = __builtin_amdgcn_exp2f(__builtin_fmaf(st0[r], SC, c1)); st0[r] = pv; sum += pv; }
#pragma unroll
  for (int r = 0; r < 16; ++r) { float pv = __builtin_amdgcn_exp2f(__builtin_fmaf(st1[r], SC, c1)); st1[r] = pv; sum += pv; }
  sum += __shfl_xor(sum, 32);
  l += sum;

  union U8 { bf16x8 v; unsigned int u[4]; };
  U8 pf[4];
#pragma unroll
  for (int j = 0; j < 4; ++j) {
    pf[0].u[j] = cvtpk(st0[2 * j],     st0[2 * j + 1]);
    pf[1].u[j] = cvtpk(st0[8 + 2 * j], st0[8 + 2 * j + 1]);
    pf[2].u[j] = cvtpk(st1[2 * j],     st1[2 * j + 1]);
    pf[3].u[j] = cvtpk(st1[8 + 2 * j], st1[8 + 2 * j + 1]);
  }

  const int ncf = (!last || has1) ? 4 : 2;
  __builtin_amdgcn_s_setprio(1);
#pragma unroll
  for (int dh = 0; dh < 2; ++dh) {
    const unsigned short* Vrow = &Vt[(dh * 32 + qi) * 64];
    f32x16 oc = dh ? o1 : o0;
#pragma unroll
    for (int c = 0; c < 4; ++c) {
      if (c >= ncf) break;
      bf16x8 vf = *(const bf16x8*)&Vrow[(((2 * c + hi) ^ swz) << 3)];
      oc = __builtin_amdgcn_mfma_f32_32x32x16_bf16(vf, pf[c].v, oc, 0, 0, 0);
    }
    if (dh) o1 = oc; else o0 = oc;
  }
  __builtin_amdgcn_s_setprio(0);
}

// ---------------------------------------------------------------------------
// Flash attention v5 (r15-verified): causal-complement pairing, 256 blocks.
// ---------------------------------------------------------------------------
__global__ __launch_bounds__(512, 2)
void gqa_attn5(const unsigned short* __restrict__ qb,
               const unsigned short* __restrict__ kb,
               const unsigned short* __restrict__ vt,
               unsigned short* __restrict__ ob) {
  __shared__ unsigned short Ks[3][4096];
  __shared__ unsigned short Vs[3][4096];

  const int tid  = threadIdx.x;
  const int lane = tid & 63;
  const int w    = tid >> 6;
  const int qi   = lane & 31;
  const int hi   = lane >> 5;

  const int go = blockIdx.x & 7;
  const int pp = blockIdx.x >> 3;
  const int b  = go >> 2;
  const int hk = go & 3;
  const int h  = hk * 8 + w;
  const int bh = b * H_ + h;

  const int qbaseA = (63 - pp) * 32;
  const int qbaseB = pp * 32;
  const int qrowA  = qbaseA + qi;
  const int qrowB  = qbaseB + qi;

  bf16x8 qfA[4], qfB[4];
  {
    const unsigned short* qpA = qb + ((size_t)bh * T_ + qrowA) * D_ + 8 * hi;
    const unsigned short* qpB = qb + ((size_t)bh * T_ + qrowB) * D_ + 8 * hi;
#pragma unroll
    for (int c = 0; c < 4; c++) {
      qfA[c] = *(const bf16x8*)(qpA + 16 * c);
      qfB[c] = *(const bf16x8*)(qpB + 16 * c);
    }
  }

  const int srow   = lane >> 3;
  const int schunk = (lane & 7) ^ srow;
  const int krow   = 8 * w + srow;
  const unsigned short* gK = kb + (size_t)(b * HK_ + hk) * T_ * D_ + (size_t)krow * D_ + schunk * 8;
  const unsigned short* gV = vt + (size_t)(b * HK_ + hk) * D_ * T_ + (size_t)krow * T_ + schunk * 8;
  unsigned short* ldsK = &Ks[0][w * 512];
  unsigned short* ldsV = &Vs[0][w * 512];

#define STAGE_KV(pbuf, kk0) do { \
    GLD16(gK + (size_t)(kk0) * D_, ldsK + (pbuf) * 4096); \
    GLD16(gV + (kk0),              ldsV + (pbuf) * 4096); \
  } while (0)

  f32x16 o0A = {}, o1A = {}, o0B = {}, o1B = {};
  float mA = -1e30f, lA = 0.f, c1A = 0.f;
  float mB = -1e30f, lB = 0.f, c1B = 0.f;
  const int swz = qi & 7;

  const int ntA = ((qbaseA + 31) >> 6) + 1;
  const int ntB = ((qbaseB + 31) >> 6) + 1;

  STAGE_KV(0, 0);
  if (ntA > 1) STAGE_KV(1, 64);

  int p = 0;
  for (int it = 0; it < ntA; ++it) {
    const int kb0 = it * 64;

    asm volatile("s_waitcnt lgkmcnt(0)" ::: "memory");
    if (it + 1 < ntA) asm volatile("s_waitcnt vmcnt(2)" ::: "memory");
    else              asm volatile("s_waitcnt vmcnt(0)" ::: "memory");
    asm volatile("s_barrier" ::: "memory");
    if (it + 2 < ntA) STAGE_KV((p + 2 > 2) ? p - 1 : p + 2, kb0 + 128);

    const unsigned short* Kt = &Ks[0][0] + p * 4096;
    const unsigned short* Vt = &Vs[0][0] + p * 4096;

    attn_qstep(Kt, Vt, qfA, o0A, o1A, mA, lA, c1A, qrowA, kb0, it == ntA - 1, qi, hi, swz);
    if (it < ntB)
      attn_qstep(Kt, Vt, qfB, o0B, o1B, mB, lB, c1B, qrowB, kb0, it == ntB - 1, qi, hi, swz);

    p = (p > 1) ? 0 : p + 1;
  }

  const float invA = 1.0f / lA;
  const float invB = 1.0f / lB;
  unsigned short* orowA = ob + (size_t)(b * T_ + qrowA) * (H_ * D_) + h * D_;
  unsigned short* orowB = ob + (size_t)(b * T_ + qrowB) * (H_ * D_) + h * D_;
#pragma unroll
  for (int dh = 0; dh < 2; ++dh) {
    const f32x16 ovA = dh ? o1A : o0A;
    const f32x16 ovB = dh ? o1B : o0B;
#pragma unroll
    for (int rg = 0; rg < 4; ++rg) {
      const int d0 = 32 * dh + 8 * rg + 4 * hi;
      ushort4 pkA, pkB;
      pkA.x = f2bf(ovA[4 * rg + 0] * invA);
      pkA.y = f2bf(ovA[4 * rg + 1] * invA);
      pkA.z = f2bf(ovA[4 * rg + 2] * invA);
      pkA.w = f2bf(ovA[4 * rg + 3] * invA);
      pkB.x = f2bf(ovB[4 * rg + 0] * invB);
      pkB.y = f2bf(ovB[4 * rg + 1] * invB);
      pkB.z = f2bf(ovB[4 * rg + 2] * invB);
      pkB.w = f2bf(ovB[4 * rg + 3] * invB);
      *(ushort4*)(orowA + d0) = pkA;
      *(ushort4*)(orowB + d0) = pkB;
    }
  }
#undef STAGE_KV
}

// ---------------------------------------------------------------------------
extern "C" void kernel_launch(void* const* d_in, const int* in_sizes, int n_in,
                              void* d_out, int out_size, void* d_ws, size_t ws_size,
                              hipStream_t stream) {
  const float* x    = (const float*)d_in[0];
  const float* cosT = (const float*)d_in[1];
  const float* sinT = (const float*)d_in[2];
  const float* wq   = (const float*)d_in[3];
  const float* wk   = (const float*)d_in[4];
  const float* wv   = (const float*)d_in[5];
  const float* wo   = (const float*)d_in[6];

  float* y    = (float*)d_out;                                  // B*T*C
  float* kout = (float*)d_out + (size_t)B_ * T_ * C_;           // B*Hk*T*D f32
  float* vout = kout + (size_t)B_ * HK_ * T_ * D_;              // B*Hk*T*D f32

  // Workspace (peak 56,623,104 B)
  char* ws = (char*)d_ws;
  unsigned short* x_bf = (unsigned short*)(ws);                 // 16,777,216
  unsigned short* o_bf = x_bf;                                  // reuse after QKV
  unsigned short* wqkv = (unsigned short*)(ws + 16777216);      // 10,485,760
  unsigned short* q_bf = (unsigned short*)(ws + 27262976);      // 16,777,216
  unsigned short* k_bf = (unsigned short*)(ws + 44040192);      //  2,097,152
  unsigned short* v_t  = (unsigned short*)(ws + 46137344);      //  2,097,152
  unsigned short* wo_bf= (unsigned short*)(ws + 48234496);      //  8,388,608 -> 56,623,104

  const int M = B_ * T_;  // 4096

  conv_all<<<17408, 256, 0, stream>>>(x, wq, wk, wv, wo, x_bf, wqkv, wo_bf);

  // QKV GEMM with fused RoPE-q/k + v reorder epilogue: M=4096, N=2560, K=2048
  gemm3<1><<<dim3(2560 / 128, M / 128), 256, 0, stream>>>(
      x_bf, wqkv, M, 2560, C_, nullptr, cosT, sinT, q_bf, k_bf, v_t, kout, vout);

  // paired-causal flash attention: 256 blocks = 1/CU, uniform load
  gqa_attn5<<<256, 512, 0, stream>>>(q_bf, k_bf, v_t, o_bf);

  // WO GEMM: M=4096, N=2048, K=2048
  gemm3<0><<<dim3(C_ / 128, M / 128), 256, 0, stream>>>(
      o_bf, wo_bf, M, C_, H_ * D_, y, nullptr, nullptr, nullptr, nullptr, nullptr, nullptr, nullptr);
}